// Round 6
// baseline (2469.390 us; speedup 1.0000x reference)
//
#include <hip/hip_runtime.h>
#include <hip/hip_bf16.h>
#include <cstdint>

#define S_LEN   4608
#define HID     2048
#define VOCAB_N 32768
#define CAPV    30.0f
#define IGNORE_IDX (-100)
#define NT512   512   // vocab partial tiles of 64 columns
#define NKT     32    // K-tiles: 2048 / 64

typedef short bf16x8 __attribute__((ext_vector_type(8)));
typedef float f32x4  __attribute__((ext_vector_type(4)));
typedef int   i32x4  __attribute__((ext_vector_type(4)));

// ---------- helpers ----------
__device__ __forceinline__ unsigned short f2bf_rtne(float f) {
    unsigned int u = __float_as_uint(f);
    unsigned int r = u + 0x7fffu + ((u >> 16) & 1u);
    return (unsigned short)(r >> 16);
}
__device__ __forceinline__ float bfr(float f) {  // fp32 -> bf16 -> fp32 (RTNE)
    unsigned int u = __float_as_uint(f);
    unsigned int r = u + 0x7fffu + ((u >> 16) & 1u);
    return __uint_as_float(r & 0xffff0000u);
}
__device__ __forceinline__ float bf_lo(unsigned int u) { return __uint_as_float(u << 16); }
__device__ __forceinline__ float bf_hi(unsigned int u) { return __uint_as_float(u & 0xffff0000u); }
__device__ __forceinline__ float bfdot2(unsigned int x, unsigned int w) {
    return bf_lo(x) * bf_lo(w) + bf_hi(x) * bf_hi(w);
}
// Reference-matched softcap: logit, logit/CAP and tanh rounded through bf16.
__device__ __forceinline__ float softcap_ref(float logit) {
    float lb = bfr(logit);
    float x  = bfr(lb / CAPV);
    float e  = __expf(2.0f * x);
    float t  = bfr((e - 1.0f) / (e + 1.0f));
    return CAPV * t;
}

// ---------- kernel 0: fp32 -> bf16 convert of hidden (+ zero the output scalar) ----------
__global__ void cvt_kernel(const float* __restrict__ h, unsigned short* __restrict__ xb,
                           float* __restrict__ out) {
    if (blockIdx.x == 0 && threadIdx.x == 0) out[0] = 0.0f;
    int i = blockIdx.x * blockDim.x + threadIdx.x;   // one float4 per thread, exact cover
    float4 v = ((const float4*)h)[i];
    ushort4 o;
    o.x = f2bf_rtne(v.x); o.y = f2bf_rtne(v.y);
    o.z = f2bf_rtne(v.z); o.w = f2bf_rtne(v.w);
    ((ushort4*)xb)[i] = o;
}

// ---------- kernel 1: 256x256 / 8-wave / BK=64 GEMM + softcap + partial sum-exp ----------
// R6 = R5 cleaned (R5 failed because a dead-draft main loop was left executing before
// the real one -> ~2x garbage accumulation; editing bug, not theory).
// Design under test: REG-STAGING (T14) instead of global_load_lds.  Evidence: dur ==
// FETCH / ~1.55 TB/s across 5 gll schedules (schedule-invariant), while the plain-load
// copy ubench sustains 6.3 TB/s on the same miss path; AITER/HK reg-stage streaming
// K-loops.  Staging = global_load_dwordx4 -> VGPR -> ds_write_b128; waits are
// compiler-counted vmcnt on SSA values; one write-visibility barrier per K-tile.
// Same XOR involution as all passing rounds: LDS slot s of row r holds global chunk
// s ^ (r&7); applied on the per-lane ds_write address.
// Tile body (tile t, CUR=t&1, NXT=t^1):
//   P1 : rd bv23(CUR); issue glA(t+1)->Areg   | MFMA Q00{av03,bv01}; BAR
//   P2 : rd av47(CUR)                         | MFMA Q01{av03,bv23}; BAR
//   P3 : dsw Breg,Areg -> NXT                 | MFMA Q10{av47,bv01}; lgkm0; BAR
//   P0': rd av03,bv01(NXT); issue glB(t+2)    | MFMA Q11{av47,bv23}; BAR
// glB slack = 4 phases, glA = 2.  Buffer WAR windows >= 2 barriers (audited).
__global__ __launch_bounds__(512, 2)
void gemm_lse_kernel(const unsigned short* __restrict__ X,
                     const unsigned short* __restrict__ W,
                     float* __restrict__ partL) {
    __shared__ __align__(16) unsigned short As[2][256 * 64];
    __shared__ __align__(16) unsigned short Bs[2][256 * 64];

    const int tid  = threadIdx.x;
    const int wid  = tid >> 6;
    const int lane = tid & 63;
    const int wr   = wid >> 2;            // 0..1 : M half of the wave grid
    const int wc   = wid & 3;             // 0..3 : N quarter
    const int q    = lane >> 4, l16 = lane & 15;
    const int tileM = blockIdx.x * 256;
    const int tileN = blockIdx.y * 256;

    // staging per-thread map: 512 threads x 16B x 4 rows = 256 rows x 8 chunks.
    const int srow = lane >> 3;                 // 0..7 (row within the wave's 8)
    const int csrc = (lane & 7) ^ srow;         // pre-swizzled global source chunk
    const unsigned short* Ag = X + (size_t)(tileM + wid * 8 + srow) * HID + csrc * 8;
    const unsigned short* Wg = W + (size_t)(tileN + wid * 8 + srow) * HID + csrc * 8;
    // ds_write target: row (wid*8+srow) + {0,64,128,192}, 16B slot (lane&7)
    const int dsw_off = (wid * 8 + srow) * 64 + (lane & 7) * 8;

    // fragment-read constants: row = .. + l16, chunk c=kk*4+q lives at slot c^(l16&7)
    const int abase = (wr * 128 + l16) * 64;
    const int bbase = (wc * 64  + l16) * 64;
    const int koff0 = ((q    ) ^ (l16 & 7)) * 8;
    const int koff1 = ((q + 4) ^ (l16 & 7)) * 8;

    bf16x8 av[8][2], bv[4][2];
    i32x4  Areg[4], Breg[4];
    f32x4  acc[8][4] = {};

#define GL_A(KT) do {                                                                     \
    const unsigned short* _g = Ag + (size_t)(KT) * 64;                                    \
    Areg[0] = *(const i32x4*)(_g);                                                        \
    Areg[1] = *(const i32x4*)(_g + (size_t)64  * HID);                                    \
    Areg[2] = *(const i32x4*)(_g + (size_t)128 * HID);                                    \
    Areg[3] = *(const i32x4*)(_g + (size_t)192 * HID);                                    \
} while (0)

#define GL_B(KT) do {                                                                     \
    const unsigned short* _g = Wg + (size_t)(KT) * 64;                                    \
    Breg[0] = *(const i32x4*)(_g);                                                        \
    Breg[1] = *(const i32x4*)(_g + (size_t)64  * HID);                                    \
    Breg[2] = *(const i32x4*)(_g + (size_t)128 * HID);                                    \
    Breg[3] = *(const i32x4*)(_g + (size_t)192 * HID);                                    \
} while (0)

#define DSW_A(BUF) do {                                                                   \
    unsigned short* _l = &As[BUF][dsw_off];                                               \
    *(i32x4*)(_l)            = Areg[0];                                                   \
    *(i32x4*)(_l +  64 * 64) = Areg[1];                                                   \
    *(i32x4*)(_l + 128 * 64) = Areg[2];                                                   \
    *(i32x4*)(_l + 192 * 64) = Areg[3];                                                   \
} while (0)

#define DSW_B(BUF) do {                                                                   \
    unsigned short* _l = &Bs[BUF][dsw_off];                                               \
    *(i32x4*)(_l)            = Breg[0];                                                   \
    *(i32x4*)(_l +  64 * 64) = Breg[1];                                                   \
    *(i32x4*)(_l + 128 * 64) = Breg[2];                                                   \
    *(i32x4*)(_l + 192 * 64) = Breg[3];                                                   \
} while (0)

// RD_A(BUF, MH): av[MH*4 .. MH*4+3][0..1]  (8x ds_read_b128)
#define RD_A(BUF, MH) do {                                                                \
    _Pragma("unroll") for (int fm = 0; fm < 4; ++fm) {                                    \
        av[(MH) * 4 + fm][0] = *(const bf16x8*)&As[BUF][abase + ((MH) * 64 + fm * 16) * 64 + koff0]; \
        av[(MH) * 4 + fm][1] = *(const bf16x8*)&As[BUF][abase + ((MH) * 64 + fm * 16) * 64 + koff1]; \
    } } while (0)

// RD_B(BUF, NH): bv[NH*2 .. NH*2+1][0..1]  (4x ds_read_b128)
#define RD_B(BUF, NH) do {                                                                \
    _Pragma("unroll") for (int fn = 0; fn < 2; ++fn) {                                    \
        bv[(NH) * 2 + fn][0] = *(const bf16x8*)&Bs[BUF][bbase + ((NH) * 32 + fn * 16) * 64 + koff0]; \
        bv[(NH) * 2 + fn][1] = *(const bf16x8*)&Bs[BUF][bbase + ((NH) * 32 + fn * 16) * 64 + koff1]; \
    } } while (0)

#define MFMAQ(MH, NH) do {                                                                \
    _Pragma("unroll") for (int kk = 0; kk < 2; ++kk)                                      \
    _Pragma("unroll") for (int fm = 0; fm < 4; ++fm)                                      \
    _Pragma("unroll") for (int fn = 0; fn < 2; ++fn)                                      \
        acc[(MH) * 4 + fm][(NH) * 2 + fn] = __builtin_amdgcn_mfma_f32_16x16x32_bf16(      \
            av[(MH) * 4 + fm][kk], bv[(NH) * 2 + fn][kk],                                 \
            acc[(MH) * 4 + fm][(NH) * 2 + fn], 0, 0, 0);                                  \
} while (0)

#define BAR()   __builtin_amdgcn_s_barrier()
#define PRIO1() __builtin_amdgcn_s_setprio(1)
#define PRIO0() __builtin_amdgcn_s_setprio(0)
#define LGKM0() do { asm volatile("s_waitcnt lgkmcnt(0)" ::: "memory");                   \
                     __builtin_amdgcn_sched_barrier(0); } while (0)

    // ---- prologue: stage tile0 via regs, read its first fragments, issue glB(1) ----
    GL_B(0); GL_A(0);
    DSW_B(0); DSW_A(0);     // compiler inserts exact counted vmcnt waits here
    LGKM0(); BAR();
    RD_A(0, 0); RD_B(0, 0); // av03, bv01 of tile0
    GL_B(1);
    BAR();

    // ---- main loop: tiles 0..29, 2 per iteration (absolute K indices) ----
    #pragma unroll 1
    for (int t = 0; t < NKT - 2; t += 2) {
        // ---- tile t (CUR=0) ----
        RD_B(0, 1);
        GL_A(t + 1);
        PRIO1(); MFMAQ(0, 0); PRIO0(); BAR();
        RD_A(0, 1);
        PRIO1(); MFMAQ(0, 1); PRIO0(); BAR();
        DSW_B(1); DSW_A(1);
        PRIO1(); MFMAQ(1, 0); PRIO0();
        LGKM0(); BAR();
        RD_A(1, 0); RD_B(1, 0);
        GL_B(t + 2);
        PRIO1(); MFMAQ(1, 1); PRIO0(); BAR();
        // ---- tile t+1 (CUR=1) ----
        RD_B(1, 1);
        GL_A(t + 2);
        PRIO1(); MFMAQ(0, 0); PRIO0(); BAR();
        RD_A(1, 1);
        PRIO1(); MFMAQ(0, 1); PRIO0(); BAR();
        DSW_B(0); DSW_A(0);
        PRIO1(); MFMAQ(1, 0); PRIO0();
        LGKM0(); BAR();
        RD_A(0, 0); RD_B(0, 0);
        GL_B(t + 3);            // t <= 28 -> t+3 <= 31, always valid
        PRIO1(); MFMAQ(1, 1); PRIO0(); BAR();
    }

    // ---- tile 30 (CUR=0): stage tile 31 into buf1; no further glB ----
    RD_B(0, 1);
    GL_A(31);
    PRIO1(); MFMAQ(0, 0); PRIO0(); BAR();
    RD_A(0, 1);
    PRIO1(); MFMAQ(0, 1); PRIO0(); BAR();
    DSW_B(1); DSW_A(1);
    PRIO1(); MFMAQ(1, 0); PRIO0();
    LGKM0(); BAR();
    RD_A(1, 0); RD_B(1, 0);
    PRIO1(); MFMAQ(1, 1); PRIO0(); BAR();

    // ---- tile 31 (CUR=1): last, no writers -> barriers only for read visibility ----
    RD_B(1, 1);
    PRIO1(); MFMAQ(0, 0); PRIO0();
    RD_A(1, 1);
    PRIO1(); MFMAQ(0, 1); PRIO0();
    PRIO1(); MFMAQ(1, 0); PRIO0();
    PRIO1(); MFMAQ(1, 1); PRIO0();

    // ---- epilogue: softcap + exp + 64-col partial sums ----
    // C layout per 16x16: col = l16 (vocab), row = q*4 + reg (seq).
    // Wave covers exactly one 64-col partL tile: ntile = blockIdx.y*4 + wc.
    const int rowbase = tileM + wr * 128;
    const int ntile   = blockIdx.y * 4 + wc;
    #pragma unroll
    for (int m = 0; m < 8; ++m) {
        #pragma unroll
        for (int r = 0; r < 4; ++r) {
            float s = 0.0f;
            #pragma unroll
            for (int n = 0; n < 4; ++n)
                s += __expf(softcap_ref(acc[m][n][r]));
            s += __shfl_xor(s, 1);
            s += __shfl_xor(s, 2);
            s += __shfl_xor(s, 4);
            s += __shfl_xor(s, 8);
            if (l16 == 0)
                partL[(size_t)(rowbase + m * 16 + q * 4 + r) * NT512 + ntile] = s;
        }
    }

#undef GL_A
#undef GL_B
#undef DSW_A
#undef DSW_B
#undef RD_A
#undef RD_B
#undef MFMAQ
#undef BAR
#undef PRIO1
#undef PRIO0
#undef LGKM0
}

// ---------- kernel 2: per-row label logit + logsumexp reduce -> atomic total ----------
__global__ void row_reduce_kernel(const unsigned short* __restrict__ X,
                                  const unsigned short* __restrict__ W,
                                  const int* __restrict__ ids,
                                  const int* __restrict__ am,
                                  const float* __restrict__ partL,
                                  float* __restrict__ out) {
    __shared__ float blk[4];
    const int wave = threadIdx.x >> 6;
    const int lane = threadIdx.x & 63;
    const int r = blockIdx.x * 4 + wave;

    int lab = IGNORE_IDX;
    if (r < S_LEN - 1 && am[r + 1] != 0) lab = ids[r + 1];
    const bool valid = (lab >= 0 && lab < VOCAB_N);

    float dot = 0.0f;
    if (valid) {
        const unsigned short* xr = X + (size_t)r   * HID;
        const unsigned short* wr = W + (size_t)lab * HID;
        #pragma unroll
        for (int c = 0; c < 4; ++c) {
            const int off = c * 512 + lane * 8;
            uint4 xu = *(const uint4*)(xr + off);
            uint4 wu = *(const uint4*)(wr + off);
            dot += bfdot2(xu.x, wu.x) + bfdot2(xu.y, wu.y) +
                   bfdot2(xu.z, wu.z) + bfdot2(xu.w, wu.w);
        }
    }
    #pragma unroll
    for (int m = 1; m < 64; m <<= 1) dot += __shfl_xor(dot, m);

    float L = 0.0f;
    const float* pr = partL + (size_t)r * NT512;
    #pragma unroll
    for (int i = 0; i < 8; ++i) L += pr[i * 64 + lane];
    #pragma unroll
    for (int m = 1; m < 64; m <<= 1) L += __shfl_xor(L, m);

    if (lane == 0) {
        float loss = 0.0f;
        if (valid) loss = logf(L) - softcap_ref(dot);
        blk[wave] = loss;
    }
    __syncthreads();
    if (threadIdx.x == 0)
        atomicAdd(out, blk[0] + blk[1] + blk[2] + blk[3]);
}

extern "C" void kernel_launch(void* const* d_in, const int* in_sizes, int n_in,
                              void* d_out, int out_size, void* d_ws, size_t ws_size,
                              hipStream_t stream) {
    const unsigned short* W  = (const unsigned short*)d_in[0];  // bf16 [V, H]
    const float*  hidden     = (const float*)d_in[1];           // fp32 [1, S, H]
    const int*    ids        = (const int*)d_in[2];             // [1, S]
    const int*    am         = (const int*)d_in[3];             // [1, S]
    float* out = (float*)d_out;

    char* ws = (char*)d_ws;
    unsigned short* Xb = (unsigned short*)ws;                          // S*H bf16
    float* partL       = (float*)(ws + (size_t)S_LEN * HID * 2);       // S*512 f32

    cvt_kernel<<<(S_LEN * HID / 4) / 256, 256, 0, stream>>>(hidden, Xb, out);

    dim3 g(S_LEN / 256, VOCAB_N / 256);    // x = M (18), y = N (128): W reuse across x
    gemm_lse_kernel<<<g, 512, 0, stream>>>(Xb, W, partL);

    row_reduce_kernel<<<S_LEN / 4, 256, 0, stream>>>(Xb, W, ids, am, partL, out);
}

// Round 7
// 1120.615 us; speedup vs baseline: 2.2036x; 2.2036x over previous
//
#include <hip/hip_runtime.h>
#include <hip/hip_bf16.h>
#include <cstdint>

#define S_LEN   4608
#define HID     2048
#define VOCAB_N 32768
#define CAPV    30.0f
#define IGNORE_IDX (-100)
#define NT512   512   // vocab partial tiles of 64 columns
#define NKS     64    // K-steps: 2048 / 32

typedef short bf16x8 __attribute__((ext_vector_type(8)));
typedef float f32x4  __attribute__((ext_vector_type(4)));

// ---------- helpers ----------
__device__ __forceinline__ unsigned short f2bf_rtne(float f) {
    unsigned int u = __float_as_uint(f);
    unsigned int r = u + 0x7fffu + ((u >> 16) & 1u);
    return (unsigned short)(r >> 16);
}
__device__ __forceinline__ float bfr(float f) {  // fp32 -> bf16 -> fp32 (RTNE)
    unsigned int u = __float_as_uint(f);
    unsigned int r = u + 0x7fffu + ((u >> 16) & 1u);
    return __uint_as_float(r & 0xffff0000u);
}
__device__ __forceinline__ float bf_lo(unsigned int u) { return __uint_as_float(u << 16); }
__device__ __forceinline__ float bf_hi(unsigned int u) { return __uint_as_float(u & 0xffff0000u); }
__device__ __forceinline__ float bfdot2(unsigned int x, unsigned int w) {
    return bf_lo(x) * bf_lo(w) + bf_hi(x) * bf_hi(w);
}
// Reference-matched softcap: logit, logit/CAP and tanh rounded through bf16.
__device__ __forceinline__ float softcap_ref(float logit) {
    float lb = bfr(logit);
    float x  = bfr(lb / CAPV);
    float e  = __expf(2.0f * x);
    float t  = bfr((e - 1.0f) / (e + 1.0f));
    return CAPV * t;
}

// ---------- kernel 0: fp32 -> bf16 convert of hidden (+ zero the output scalar) ----------
__global__ void cvt_kernel(const float* __restrict__ h, unsigned short* __restrict__ xb,
                           float* __restrict__ out) {
    if (blockIdx.x == 0 && threadIdx.x == 0) out[0] = 0.0f;
    int i = blockIdx.x * blockDim.x + threadIdx.x;   // one float4 per thread, exact cover
    float4 v = ((const float4*)h)[i];
    ushort4 o;
    o.x = f2bf_rtne(v.x); o.y = f2bf_rtne(v.y);
    o.z = f2bf_rtne(v.z); o.w = f2bf_rtne(v.w);
    ((ushort4*)xb)[i] = o;
}

// ---------- kernel 1: 256x256 / 16-wave / BK=32 double-buffered GEMM + softcap + sum-exp ----
// R7 synthesis of the series:
//  * Staged-byte accounting: R0 (128^2, ~3.7 blk/CU) staged 9.2 GB @ 11.7 TB/s = 786 us;
//    R2-R4 (256^2, 8 lockstep waves) staged 4.6 GB @ 5.8 TB/s = ~790 us.  Delivery rate
//    scales with wave-level concurrency (Little's law), so the 256^2 byte minimum only
//    pays if concurrency is restored.  R6 (reg-staging) spilled: 4 GB scratch writes.
//  * This kernel: 256^2 tile (minimum staged bytes = 4.6 GB) with SIXTEEN waves
//    (1024 thr), per-wave 64x64 output -> acc 64 AGPR, ~110 total regs -> 4 waves/SIMD.
//    BK=32 double-buffer (64 KB LDS), ONE __syncthreads per K-step; stage of tile t+1
//    issues right after the barrier and lands during tile t's compute; 16 waves x 2 gll
//    per window = R0-level in-flight bytes per CU.
//  * Staging map, XOR involution, fragment layout, epilogue and FP accumulation order
//    are verbatim R0 (proven): slot s of row r holds global chunk s ^ ((r>>2)&3);
//    fragment read offset swz = (q ^ (l16>>2))*8 -> conflict-free ds_read_b128.
__global__ __launch_bounds__(1024, 4)
void gemm_lse_kernel(const unsigned short* __restrict__ X,
                     const unsigned short* __restrict__ W,
                     float* __restrict__ partL) {
    __shared__ __align__(16) unsigned short As[2][256 * 32];
    __shared__ __align__(16) unsigned short Bs[2][256 * 32];

    const int tid  = threadIdx.x;
    const int wid  = tid >> 6;            // 0..15
    const int lane = tid & 63;
    const int wr   = wid >> 2;            // 0..3 : M quarter (64 rows)
    const int wc   = wid & 3;             // 0..3 : N quarter (64 cols)
    const int q    = lane >> 4, l16 = lane & 15;
    const int tileM = blockIdx.x * 256;
    const int tileN = blockIdx.y * 256;

    // staging lane map (R0-proven): wave covers 16 rows; lane -> row wid*16 + (lane>>2),
    // 16B slot (lane&3).  Slot s of row r receives GLOBAL chunk s ^ ((r>>2)&3):
    const int lr = lane >> 2;
    const int cg = (lane & 3) ^ ((lane >> 4) & 3);
    const unsigned short* Ag = X + (size_t)(tileM + wid * 16 + lr) * HID + cg * 8;
    const unsigned short* Wg = W + (size_t)(tileN + wid * 16 + lr) * HID + cg * 8;

    // fragment read: global chunk q of row (.. + l16) lives at slot q ^ (l16>>2)
    const int swz   = (q ^ (l16 >> 2)) * 8;
    const int abase = (wr * 64 + l16) * 32 + swz;
    const int bbase = (wc * 64 + l16) * 32 + swz;

    f32x4 acc[4][4] = {};

#define STAGE(BUF, T) do {                                                                \
    __builtin_amdgcn_global_load_lds(                                                     \
        (const __attribute__((address_space(1))) void*)(Ag + (size_t)(T) * 32),           \
        (__attribute__((address_space(3))) void*)&As[BUF][wid * 512], 16, 0, 0);          \
    __builtin_amdgcn_global_load_lds(                                                     \
        (const __attribute__((address_space(1))) void*)(Wg + (size_t)(T) * 32),           \
        (__attribute__((address_space(3))) void*)&Bs[BUF][wid * 512], 16, 0, 0);          \
} while (0)

#define COMPUTE(BUF) do {                                                                 \
    bf16x8 av[4], bv[4];                                                                  \
    _Pragma("unroll") for (int f = 0; f < 4; ++f) {                                       \
        av[f] = *(const bf16x8*)&As[BUF][abase + f * 512];                                \
        bv[f] = *(const bf16x8*)&Bs[BUF][bbase + f * 512];                                \
    }                                                                                     \
    _Pragma("unroll") for (int m = 0; m < 4; ++m)                                         \
    _Pragma("unroll") for (int n = 0; n < 4; ++n)                                         \
        acc[m][n] = __builtin_amdgcn_mfma_f32_16x16x32_bf16(av[m], bv[n],                 \
                                                            acc[m][n], 0, 0, 0);          \
} while (0)

    // prologue: stage K-step 0 into buf0
    STAGE(0, 0);

    // main loop: one barrier per K-step; stage t+1 overlaps compute of t.
    // Safety: barrier at top of step t drains the gll into buf[cur] (issued at t-1)
    // and guarantees all waves finished reading buf[cur^1] (read at t-1) before the
    // new stage overwrites it.
    #pragma unroll 1
    for (int t = 0; t < NKS - 2; t += 2) {
        __syncthreads();
        STAGE(1, t + 1);
        COMPUTE(0);
        __syncthreads();
        STAGE(0, t + 2);
        COMPUTE(1);
    }
    // tail: steps 62, 63
    __syncthreads();
    STAGE(1, NKS - 1);
    COMPUTE(0);
    __syncthreads();
    COMPUTE(1);

    // ---- epilogue: softcap + exp + 64-col partial sums ----
    // C layout per 16x16: col = l16 (vocab), row = q*4 + r (seq).
    // Wave covers exactly one 64-col partL tile: ntile = blockIdx.y*4 + wc.
    const int rowbase = tileM + wr * 64;
    const int ntile   = blockIdx.y * 4 + wc;
    #pragma unroll
    for (int m = 0; m < 4; ++m) {
        #pragma unroll
        for (int r = 0; r < 4; ++r) {
            float s = 0.0f;
            #pragma unroll
            for (int n = 0; n < 4; ++n)
                s += __expf(softcap_ref(acc[m][n][r]));
            s += __shfl_xor(s, 1);
            s += __shfl_xor(s, 2);
            s += __shfl_xor(s, 4);
            s += __shfl_xor(s, 8);
            if (l16 == 0)
                partL[(size_t)(rowbase + m * 16 + q * 4 + r) * NT512 + ntile] = s;
        }
    }

#undef STAGE
#undef COMPUTE
}

// ---------- kernel 2: per-row label logit + logsumexp reduce -> atomic total ----------
__global__ void row_reduce_kernel(const unsigned short* __restrict__ X,
                                  const unsigned short* __restrict__ W,
                                  const int* __restrict__ ids,
                                  const int* __restrict__ am,
                                  const float* __restrict__ partL,
                                  float* __restrict__ out) {
    __shared__ float blk[4];
    const int wave = threadIdx.x >> 6;
    const int lane = threadIdx.x & 63;
    const int r = blockIdx.x * 4 + wave;

    int lab = IGNORE_IDX;
    if (r < S_LEN - 1 && am[r + 1] != 0) lab = ids[r + 1];
    const bool valid = (lab >= 0 && lab < VOCAB_N);

    float dot = 0.0f;
    if (valid) {
        const unsigned short* xr = X + (size_t)r   * HID;
        const unsigned short* wr = W + (size_t)lab * HID;
        #pragma unroll
        for (int c = 0; c < 4; ++c) {
            const int off = c * 512 + lane * 8;
            uint4 xu = *(const uint4*)(xr + off);
            uint4 wu = *(const uint4*)(wr + off);
            dot += bfdot2(xu.x, wu.x) + bfdot2(xu.y, wu.y) +
                   bfdot2(xu.z, wu.z) + bfdot2(xu.w, wu.w);
        }
    }
    #pragma unroll
    for (int m = 1; m < 64; m <<= 1) dot += __shfl_xor(dot, m);

    float L = 0.0f;
    const float* pr = partL + (size_t)r * NT512;
    #pragma unroll
    for (int i = 0; i < 8; ++i) L += pr[i * 64 + lane];
    #pragma unroll
    for (int m = 1; m < 64; m <<= 1) L += __shfl_xor(L, m);

    if (lane == 0) {
        float loss = 0.0f;
        if (valid) loss = logf(L) - softcap_ref(dot);
        blk[wave] = loss;
    }
    __syncthreads();
    if (threadIdx.x == 0)
        atomicAdd(out, blk[0] + blk[1] + blk[2] + blk[3]);
}

extern "C" void kernel_launch(void* const* d_in, const int* in_sizes, int n_in,
                              void* d_out, int out_size, void* d_ws, size_t ws_size,
                              hipStream_t stream) {
    const unsigned short* W  = (const unsigned short*)d_in[0];  // bf16 [V, H]
    const float*  hidden     = (const float*)d_in[1];           // fp32 [1, S, H]
    const int*    ids        = (const int*)d_in[2];             // [1, S]
    const int*    am         = (const int*)d_in[3];             // [1, S]
    float* out = (float*)d_out;

    char* ws = (char*)d_ws;
    unsigned short* Xb = (unsigned short*)ws;                          // S*H bf16
    float* partL       = (float*)(ws + (size_t)S_LEN * HID * 2);       // S*512 f32

    cvt_kernel<<<(S_LEN * HID / 4) / 256, 256, 0, stream>>>(hidden, Xb, out);

    dim3 g(S_LEN / 256, VOCAB_N / 256);    // x = M (18), y = N (128): W reuse across x
    gemm_lse_kernel<<<g, 1024, 0, stream>>>(Xb, W, partL);

    row_reduce_kernel<<<S_LEN / 4, 256, 0, stream>>>(Xb, W, ids, am, partL, out);
}

// Round 8
// 1116.441 us; speedup vs baseline: 2.2118x; 1.0037x over previous
//
#include <hip/hip_runtime.h>
#include <hip/hip_bf16.h>
#include <cstdint>

#define S_LEN   4608
#define HID     2048
#define VOCAB_N 32768
#define CAPV    30.0f
#define IGNORE_IDX (-100)
#define NT512   512   // vocab partial tiles of 64 columns
#define NKS     64    // K-steps: 2048 / 32

typedef short bf16x8 __attribute__((ext_vector_type(8)));
typedef float f32x4  __attribute__((ext_vector_type(4)));

// ---------- helpers ----------
__device__ __forceinline__ unsigned short f2bf_rtne(float f) {
    unsigned int u = __float_as_uint(f);
    unsigned int r = u + 0x7fffu + ((u >> 16) & 1u);
    return (unsigned short)(r >> 16);
}
__device__ __forceinline__ float bfr(float f) {  // fp32 -> bf16 -> fp32 (RTNE)
    unsigned int u = __float_as_uint(f);
    unsigned int r = u + 0x7fffu + ((u >> 16) & 1u);
    return __uint_as_float(r & 0xffff0000u);
}
__device__ __forceinline__ float bf_lo(unsigned int u) { return __uint_as_float(u << 16); }
__device__ __forceinline__ float bf_hi(unsigned int u) { return __uint_as_float(u & 0xffff0000u); }
__device__ __forceinline__ float bfdot2(unsigned int x, unsigned int w) {
    return bf_lo(x) * bf_lo(w) + bf_hi(x) * bf_hi(w);
}
// Reference-matched softcap: logit, logit/CAP and tanh rounded through bf16.
__device__ __forceinline__ float softcap_ref(float logit) {
    float lb = bfr(logit);
    float x  = bfr(lb / CAPV);
    float e  = __expf(2.0f * x);
    float t  = bfr((e - 1.0f) / (e + 1.0f));
    return CAPV * t;
}

// ---------- kernel 0: fp32 -> bf16 convert (+ zero output scalar and XCD counters) ----
__global__ void cvt_kernel(const float* __restrict__ h, unsigned short* __restrict__ xb,
                           float* __restrict__ out, unsigned int* __restrict__ cnt) {
    if (blockIdx.x == 0) {
        if (threadIdx.x == 0) out[0] = 0.0f;
        if (threadIdx.x < 8)  cnt[threadIdx.x] = 0u;
    }
    int i = blockIdx.x * blockDim.x + threadIdx.x;   // one float4 per thread, exact cover
    float4 v = ((const float4*)h)[i];
    ushort4 o;
    o.x = f2bf_rtne(v.x); o.y = f2bf_rtne(v.y);
    o.z = f2bf_rtne(v.z); o.w = f2bf_rtne(v.w);
    ((ushort4*)xb)[i] = o;
}

// ---------- kernel 1: 256x256 / 16-wave / BK=32 dbuf GEMM + softcap + sum-exp ----------
// R8 change vs R7: RUNTIME-XCD work claiming.  Series invariant: dur == FETCH/1.4TB/s
// (R0/R2/R4/R7; staged bytes, occupancy, schedule, conflicts all varied with no effect)
// -> binding resource is L2-fill traffic.  FETCH ~1.1GB ~= 8x unique because each
// W-panel's 18 sharers are scattered over all 8 XCDs (R4's blind bid&7 remap was a null
// -> the dispatch mapping guess was wrong).  Fix: read the PHYSICAL die id via
// s_getreg(HW_REG_XCC_ID) [m09-verified] + per-XCD atomic work queues with stealing
// (deadlock-free: a partition reports full iff its 288 items were all claimed).
// Partition: XCD q (qa=q&1, qb=q>>1) owns xt in [qa*9, qa*9+9) x yt in [qb*32, qb*32+32)
// = 288 items.  Claim c snakes in 9x8 windows: the ~64 concurrent blocks per XCD share
// 7-8 W-panels + 9 X-panels -> per-XCD fill ~= W 32MB once + X 9MB x 4 windows ~= 68MB,
// ~545MB chip-wide (half of R7).  Kernel body = R7 verbatim (clean A/B).
__global__ __launch_bounds__(1024, 4)
void gemm_lse_kernel(const unsigned short* __restrict__ X,
                     const unsigned short* __restrict__ W,
                     float* __restrict__ partL,
                     unsigned int* __restrict__ cnt) {
    __shared__ __align__(16) unsigned short As[2][256 * 32];
    __shared__ __align__(16) unsigned short Bs[2][256 * 32];
    __shared__ int sh_item;

    const int tid  = threadIdx.x;
    const int wid  = tid >> 6;            // 0..15
    const int lane = tid & 63;
    const int wr   = wid >> 2;            // 0..3 : M quarter (64 rows)
    const int wc   = wid & 3;             // 0..3 : N quarter (64 cols)
    const int q    = lane >> 4, l16 = lane & 15;

    // ---- claim a work item on this block's physical XCD ----
    if (tid == 0) {
        unsigned int xcc;
        asm volatile("s_getreg_b32 %0, hwreg(HW_REG_XCC_ID)" : "=s"(xcc));
        xcc &= 7u;
        int item = -1;
        #pragma unroll 1
        for (int p = 0; p < 8 && item < 0; ++p) {
            unsigned int part = (xcc + p) & 7u;
            unsigned int c = atomicAdd(&cnt[part], 1u);
            if (c < 288u) item = (int)(part * 288u + c);
        }
        sh_item = item;
    }
    __syncthreads();
    const int item = sh_item;
    const int part = item / 288, c = item % 288;
    const int qa = part & 1, qb = part >> 1;
    const int wy = c / 72, rem = c % 72;
    const int xt = qa * 9  + rem % 9;
    const int yt = qb * 32 + wy * 8 + rem / 9;
    const int tileM = xt * 256;
    const int tileN = yt * 256;

    // staging lane map (R0-proven): wave covers 16 rows; lane -> row wid*16 + (lane>>2),
    // 16B slot (lane&3).  Slot s of row r receives GLOBAL chunk s ^ ((r>>2)&3):
    const int lr = lane >> 2;
    const int cg = (lane & 3) ^ ((lane >> 4) & 3);
    const unsigned short* Ag = X + (size_t)(tileM + wid * 16 + lr) * HID + cg * 8;
    const unsigned short* Wg = W + (size_t)(tileN + wid * 16 + lr) * HID + cg * 8;

    // fragment read: global chunk q of row (.. + l16) lives at slot q ^ (l16>>2)
    const int swz   = (q ^ (l16 >> 2)) * 8;
    const int abase = (wr * 64 + l16) * 32 + swz;
    const int bbase = (wc * 64 + l16) * 32 + swz;

    f32x4 acc[4][4] = {};

#define STAGE(BUF, T) do {                                                                \
    __builtin_amdgcn_global_load_lds(                                                     \
        (const __attribute__((address_space(1))) void*)(Ag + (size_t)(T) * 32),           \
        (__attribute__((address_space(3))) void*)&As[BUF][wid * 512], 16, 0, 0);          \
    __builtin_amdgcn_global_load_lds(                                                     \
        (const __attribute__((address_space(1))) void*)(Wg + (size_t)(T) * 32),           \
        (__attribute__((address_space(3))) void*)&Bs[BUF][wid * 512], 16, 0, 0);          \
} while (0)

#define COMPUTE(BUF) do {                                                                 \
    bf16x8 av[4], bv[4];                                                                  \
    _Pragma("unroll") for (int f = 0; f < 4; ++f) {                                       \
        av[f] = *(const bf16x8*)&As[BUF][abase + f * 512];                                \
        bv[f] = *(const bf16x8*)&Bs[BUF][bbase + f * 512];                                \
    }                                                                                     \
    _Pragma("unroll") for (int m = 0; m < 4; ++m)                                         \
    _Pragma("unroll") for (int n = 0; n < 4; ++n)                                         \
        acc[m][n] = __builtin_amdgcn_mfma_f32_16x16x32_bf16(av[m], bv[n],                 \
                                                            acc[m][n], 0, 0, 0);          \
} while (0)

    // prologue: stage K-step 0 into buf0
    STAGE(0, 0);

    // main loop: one barrier per K-step; stage t+1 overlaps compute of t.
    #pragma unroll 1
    for (int t = 0; t < NKS - 2; t += 2) {
        __syncthreads();
        STAGE(1, t + 1);
        COMPUTE(0);
        __syncthreads();
        STAGE(0, t + 2);
        COMPUTE(1);
    }
    // tail: steps 62, 63
    __syncthreads();
    STAGE(1, NKS - 1);
    COMPUTE(0);
    __syncthreads();
    COMPUTE(1);

    // ---- epilogue: softcap + exp + 64-col partial sums ----
    // C layout per 16x16: col = l16 (vocab), row = q*4 + r (seq).
    // Wave covers exactly one 64-col partL tile: ntile = yt*4 + wc.
    const int rowbase = tileM + wr * 64;
    const int ntile   = yt * 4 + wc;
    #pragma unroll
    for (int m = 0; m < 4; ++m) {
        #pragma unroll
        for (int r = 0; r < 4; ++r) {
            float s = 0.0f;
            #pragma unroll
            for (int n = 0; n < 4; ++n)
                s += __expf(softcap_ref(acc[m][n][r]));
            s += __shfl_xor(s, 1);
            s += __shfl_xor(s, 2);
            s += __shfl_xor(s, 4);
            s += __shfl_xor(s, 8);
            if (l16 == 0)
                partL[(size_t)(rowbase + m * 16 + q * 4 + r) * NT512 + ntile] = s;
        }
    }

#undef STAGE
#undef COMPUTE
}

// ---------- kernel 2: per-row label logit + logsumexp reduce -> atomic total ----------
__global__ void row_reduce_kernel(const unsigned short* __restrict__ X,
                                  const unsigned short* __restrict__ W,
                                  const int* __restrict__ ids,
                                  const int* __restrict__ am,
                                  const float* __restrict__ partL,
                                  float* __restrict__ out) {
    __shared__ float blk[4];
    const int wave = threadIdx.x >> 6;
    const int lane = threadIdx.x & 63;
    const int r = blockIdx.x * 4 + wave;

    int lab = IGNORE_IDX;
    if (r < S_LEN - 1 && am[r + 1] != 0) lab = ids[r + 1];
    const bool valid = (lab >= 0 && lab < VOCAB_N);

    float dot = 0.0f;
    if (valid) {
        const unsigned short* xr = X + (size_t)r   * HID;
        const unsigned short* wr = W + (size_t)lab * HID;
        #pragma unroll
        for (int c = 0; c < 4; ++c) {
            const int off = c * 512 + lane * 8;
            uint4 xu = *(const uint4*)(xr + off);
            uint4 wu = *(const uint4*)(wr + off);
            dot += bfdot2(xu.x, wu.x) + bfdot2(xu.y, wu.y) +
                   bfdot2(xu.z, wu.z) + bfdot2(xu.w, wu.w);
        }
    }
    #pragma unroll
    for (int m = 1; m < 64; m <<= 1) dot += __shfl_xor(dot, m);

    float L = 0.0f;
    const float* pr = partL + (size_t)r * NT512;
    #pragma unroll
    for (int i = 0; i < 8; ++i) L += pr[i * 64 + lane];
    #pragma unroll
    for (int m = 1; m < 64; m <<= 1) L += __shfl_xor(L, m);

    if (lane == 0) {
        float loss = 0.0f;
        if (valid) loss = logf(L) - softcap_ref(dot);
        blk[wave] = loss;
    }
    __syncthreads();
    if (threadIdx.x == 0)
        atomicAdd(out, blk[0] + blk[1] + blk[2] + blk[3]);
}

extern "C" void kernel_launch(void* const* d_in, const int* in_sizes, int n_in,
                              void* d_out, int out_size, void* d_ws, size_t ws_size,
                              hipStream_t stream) {
    const unsigned short* W  = (const unsigned short*)d_in[0];  // bf16 [V, H]
    const float*  hidden     = (const float*)d_in[1];           // fp32 [1, S, H]
    const int*    ids        = (const int*)d_in[2];             // [1, S]
    const int*    am         = (const int*)d_in[3];             // [1, S]
    float* out = (float*)d_out;

    char* ws = (char*)d_ws;
    unsigned short* Xb = (unsigned short*)ws;                          // S*H bf16
    float* partL       = (float*)(ws + (size_t)S_LEN * HID * 2);       // S*512 f32
    unsigned int* cnt  = (unsigned int*)(ws + (size_t)S_LEN * HID * 2
                                            + (size_t)S_LEN * NT512 * 4); // 8 uints

    cvt_kernel<<<(S_LEN * HID / 4) / 256, 256, 0, stream>>>(hidden, Xb, out, cnt);

    // 1D grid; physical-XCD work claiming inside the kernel (2304 items)
    gemm_lse_kernel<<<(S_LEN / 256) * (VOCAB_N / 256), 1024, 0, stream>>>(Xb, W, partL, cnt);

    row_reduce_kernel<<<S_LEN / 4, 256, 0, stream>>>(Xb, W, ids, am, partL, out);
}